// Round 6
// baseline (132.326 us; speedup 1.0000x reference)
//
#include <hip/hip_runtime.h>
#include <math.h>

#define BB 2048
#define MM 1024
#define DD 64
#define NEG_INF_F (-1e30f)

__device__ __forceinline__ float wredsum(float v) {
#pragma unroll
  for (int o = 32; o > 0; o >>= 1) v += __shfl_down(v, o);
  return v;
}
__device__ __forceinline__ float wredmax(float v) {
#pragma unroll
  for (int o = 32; o > 0; o >>= 1) v = fmaxf(v, __shfl_down(v, o));
  return v;
}

// Full algebraic collapse:
//   scores_m = (x_m . c4 + c0) / 8,      c4 = W_in @ (Wk @ (seed @ Wq)), c0 = b_in . kq
//   sB       = xbar . d4 + d0,           u  = Wv @ (Wo @ wl2)
//                                        d4 = W_in @ u, d0 = b_in.u + b_o.wl2 + b_loc
//   (pooled = (xbar@W_in + b_in) @ Wv since sum(attn)=1; sB is linear in feat)
//   out_b    = (sum w^2 A A^T)^-1 (sum w^2 A r)   -- pinv at full column rank
__global__ __launch_bounds__(256) void wls_fused(
    const float* __restrict__ x,       // B*M*4
    const int*   __restrict__ pad,     // B*M (bool -> int32)
    const float* __restrict__ W_in,    // 4*64
    const float* __restrict__ b_in,    // 64
    const float* __restrict__ seed,    // 64
    const float* __restrict__ Wq,      // 64*64
    const float* __restrict__ Wk,      // 64*64
    const float* __restrict__ Wv,      // 64*64
    const float* __restrict__ Wo,      // 64*64
    const float* __restrict__ b_o,     // 64
    const float* __restrict__ w_loc,   // 68
    const float* __restrict__ b_loc,   // 1
    const float* __restrict__ prelu_a, // 1
    float* __restrict__ out)           // B*4
{
  const int tid  = threadIdx.x;
  const int b    = blockIdx.x;
  const int wave = tid >> 6;
  const int lane = tid & 63;

  __shared__ float qv[DD], kqv[DD], tv[DD], uv[DD];
  __shared__ float cst[10];      // [0..3]=c4, [4]=c0, [5..8]=d4, [9]=d0
  __shared__ float rbuf[4][16];
  __shared__ float bcast[8];     // [0]=Z, [1..4]=sum(e*x)

  // ---- issue this block's 1024 x-rows + mask loads first (coalesced float4) ----
  const float4* x4 = (const float4*)(x + (size_t)b * MM * 4);
  float4 xr[4];
  int mk[4];
#pragma unroll
  for (int k2 = 0; k2 < 4; ++k2) {
    xr[k2] = x4[tid + 256 * k2];
    mk[k2] = pad[(size_t)b * MM + tid + 256 * k2];
  }

  // ---- constants, two parallel wave chains (overlap with x-load latency) ----
  if (wave == 0) {            // q = seed @ Wq
    float acc = 0.f;
    for (int e = 0; e < DD; ++e) acc += seed[e] * Wq[e * DD + lane];
    qv[lane] = acc;
  } else if (wave == 1) {     // t = Wo @ wl2
    float acc = 0.f;
    for (int j = 0; j < DD; ++j) acc += Wo[lane * DD + j] * w_loc[4 + j];
    tv[lane] = acc;
  }
  __syncthreads();
  if (wave == 0) {            // kq = Wk @ q
    float acc = 0.f;
    for (int d = 0; d < DD; ++d) acc += Wk[lane * DD + d] * qv[d];
    kqv[lane] = acc;
  } else if (wave == 1) {     // u = Wv @ t
    float acc = 0.f;
    for (int j = 0; j < DD; ++j) acc += Wv[lane * DD + j] * tv[j];
    uv[lane] = acc;
  }
  __syncthreads();
  if (tid < 4) {              // c4
    float acc = 0.f;
    for (int e = 0; e < DD; ++e) acc += W_in[tid * DD + e] * kqv[e];
    cst[tid] = acc;
  } else if (tid == 4) {      // c0
    float acc = 0.f;
    for (int e = 0; e < DD; ++e) acc += b_in[e] * kqv[e];
    cst[4] = acc;
  } else if (tid >= 5 && tid < 9) {  // d4
    float acc = 0.f;
    for (int e = 0; e < DD; ++e) acc += W_in[(tid - 5) * DD + e] * uv[e];
    cst[tid] = acc;
  } else if (tid == 9) {      // d0
    float acc = 0.f;
    for (int e = 0; e < DD; ++e) acc += b_in[e] * uv[e] + b_o[e] * w_loc[4 + e];
    cst[9] = acc + b_loc[0];
  }
  __syncthreads();

  const float c40 = cst[0], c41 = cst[1], c42 = cst[2], c43 = cst[3], c0 = cst[4];
  const float d40 = cst[5], d41 = cst[6], d42 = cst[7], d43 = cst[8], d0 = cst[9];

  // ---- scores, masked; block max ----
  float sc[4];
  float pmax = -INFINITY;
#pragma unroll
  for (int k2 = 0; k2 < 4; ++k2) {
    float s = (xr[k2].x * c40 + xr[k2].y * c41 + xr[k2].z * c42 + xr[k2].w * c43 + c0) * 0.125f;
    if (mk[k2]) s = NEG_INF_F;
    sc[k2] = s;
    pmax = fmaxf(pmax, s);
  }
  pmax = wredmax(pmax);
  if (lane == 0) rbuf[wave][0] = pmax;
  __syncthreads();
  const float smax = fmaxf(fmaxf(rbuf[0][0], rbuf[1][0]), fmaxf(rbuf[2][0], rbuf[3][0]));
  __syncthreads();  // rbuf reused below

  // ---- softmax partials: Z and sum(exp * x) ----
  float se = 0.f, sx0 = 0.f, sx1 = 0.f, sx2 = 0.f, sx3 = 0.f;
#pragma unroll
  for (int k2 = 0; k2 < 4; ++k2) {
    float e = expf(sc[k2] - smax);  // masked rows -> 0
    se += e;
    sx0 += e * xr[k2].x; sx1 += e * xr[k2].y; sx2 += e * xr[k2].z; sx3 += e * xr[k2].w;
  }
  {
    float v5[5] = {se, sx0, sx1, sx2, sx3};
#pragma unroll
    for (int j = 0; j < 5; ++j) {
      float r = wredsum(v5[j]);
      if (lane == 0) rbuf[wave][j] = r;
    }
  }
  __syncthreads();
  if (tid < 5) bcast[tid] = rbuf[0][tid] + rbuf[1][tid] + rbuf[2][tid] + rbuf[3][tid];
  __syncthreads();

  // ---- sB directly from xbar (no matvec chain) ----
  const float Z = bcast[0];
  const float xb0 = bcast[1] / Z, xb1 = bcast[2] / Z, xb2 = bcast[3] / Z, xb3 = bcast[4] / Z;
  const float sB = xb0 * d40 + xb1 * d41 + xb2 * d42 + xb3 * d43 + d0;

  // ---- WLS accumulation: G = sum w^2 A A^T (10), rhs = sum w^2 A r (4) ----
  const float aP = prelu_a[0];
  const float wl0 = w_loc[0], wl1 = w_loc[1], wl2 = w_loc[2], wl3 = w_loc[3];

  float g0 = 0.f, g1 = 0.f, g2 = 0.f, g3 = 0.f, g4 = 0.f, g5 = 0.f, g6 = 0.f,
        g7 = 0.f, g8 = 0.f, g9 = 0.f, r0 = 0.f, r1 = 0.f, r2 = 0.f, r3 = 0.f;
#pragma unroll
  for (int k2 = 0; k2 < 4; ++k2) {
    const float x0 = xr[k2].x, x1 = xr[k2].y, x2 = xr[k2].z, x3 = xr[k2].w;
    float z = x0 * wl0 + x1 * wl1 + x2 * wl2 + x3 * wl3 + sB;
    float w = (z >= 0.f) ? z : aP * z;
    if (mk[k2]) w = 0.f;
    const float w2 = w * w;
    // A = (-x1,-x2,-x3,1), r = x0
    g0 += w2 * x1 * x1; g1 += w2 * x1 * x2; g2 += w2 * x1 * x3; g3 -= w2 * x1;
    g4 += w2 * x2 * x2; g5 += w2 * x2 * x3; g6 -= w2 * x2;
    g7 += w2 * x3 * x3; g8 -= w2 * x3;
    g9 += w2;
    r0 -= w2 * x1 * x0; r1 -= w2 * x2 * x0; r2 -= w2 * x3 * x0; r3 += w2 * x0;
  }
  {
    float vals[14] = {g0, g1, g2, g3, g4, g5, g6, g7, g8, g9, r0, r1, r2, r3};
#pragma unroll
    for (int j = 0; j < 14; ++j) {
      float r = wredsum(vals[j]);
      if (lane == 0) rbuf[wave][j] = r;
    }
  }
  __syncthreads();

  // ---- solve 4x4 normal equations (double, partial pivoting) on thread 0 ----
  if (tid == 0) {
    double s14[14];
#pragma unroll
    for (int j = 0; j < 14; ++j)
      s14[j] = (double)rbuf[0][j] + (double)rbuf[1][j] +
               (double)rbuf[2][j] + (double)rbuf[3][j];
    double G[4][5];
    G[0][0] = s14[0]; G[0][1] = s14[1]; G[0][2] = s14[2]; G[0][3] = s14[3]; G[0][4] = s14[10];
    G[1][0] = s14[1]; G[1][1] = s14[4]; G[1][2] = s14[5]; G[1][3] = s14[6]; G[1][4] = s14[11];
    G[2][0] = s14[2]; G[2][1] = s14[5]; G[2][2] = s14[7]; G[2][3] = s14[8]; G[2][4] = s14[12];
    G[3][0] = s14[3]; G[3][1] = s14[6]; G[3][2] = s14[8]; G[3][3] = s14[9]; G[3][4] = s14[13];

    for (int c = 0; c < 4; ++c) {
      int p = c; double mv = fabs(G[c][c]);
      for (int rr = c + 1; rr < 4; ++rr)
        if (fabs(G[rr][c]) > mv) { mv = fabs(G[rr][c]); p = rr; }
      if (p != c)
        for (int j = c; j < 5; ++j) { double t = G[c][j]; G[c][j] = G[p][j]; G[p][j] = t; }
      const double inv = 1.0 / G[c][c];
      for (int rr = c + 1; rr < 4; ++rr) {
        const double f = G[rr][c] * inv;
        for (int j = c; j < 5; ++j) G[rr][j] -= f * G[c][j];
      }
    }
    double y[4];
    for (int c = 3; c >= 0; --c) {
      double acc = G[c][4];
      for (int j = c + 1; j < 4; ++j) acc -= G[c][j] * y[j];
      y[c] = acc / G[c][c];
    }
    float4 o;
    o.x = (float)y[0]; o.y = (float)y[1]; o.z = (float)y[2]; o.w = (float)y[3];
    *(float4*)(out + (size_t)b * 4) = o;
  }
}

extern "C" void kernel_launch(void* const* d_in, const int* in_sizes, int n_in,
                              void* d_out, int out_size, void* d_ws, size_t ws_size,
                              hipStream_t stream) {
  const float* x       = (const float*)d_in[0];
  const int*   pad     = (const int*)d_in[1];
  const float* W_in    = (const float*)d_in[2];
  const float* b_in    = (const float*)d_in[3];
  const float* seed    = (const float*)d_in[4];
  const float* Wq      = (const float*)d_in[5];
  const float* Wk      = (const float*)d_in[6];
  const float* Wv      = (const float*)d_in[7];
  const float* Wo      = (const float*)d_in[8];
  const float* b_o     = (const float*)d_in[9];
  const float* w_loc   = (const float*)d_in[10];
  const float* b_loc   = (const float*)d_in[11];
  const float* prelu_a = (const float*)d_in[12];
  float* out = (float*)d_out;

  wls_fused<<<dim3(BB), dim3(256), 0, stream>>>(
      x, pad, W_in, b_in, seed, Wq, Wk, Wv, Wo, b_o, w_loc, b_loc, prelu_a, out);
}

// Round 8
// 117.523 us; speedup vs baseline: 1.1260x; 1.1260x over previous
//
#include <hip/hip_runtime.h>
#include <math.h>

#define BB 2048
#define MM 1024
#define DD 64
#define NEG_INF_F (-1e30f)

// ---------------------------------------------------------------------------
// Kernel 1: one block computes the 10 batch-independent constants into d_ws.
//   c4 = W_in @ (Wk @ (seed @ Wq)),  c0 = b_in . (Wk @ q)     [score collapse]
//   d4 = W_in @ (Wv @ (Wo @ wl2)),   d0 = b_in.u + b_o.wl2 + b_loc  [sB collapse]
// ---------------------------------------------------------------------------
__global__ __launch_bounds__(128) void consts_kernel(
    const float* __restrict__ W_in, const float* __restrict__ b_in,
    const float* __restrict__ seed, const float* __restrict__ Wq,
    const float* __restrict__ Wk,   const float* __restrict__ Wv,
    const float* __restrict__ Wo,   const float* __restrict__ b_o,
    const float* __restrict__ w_loc, const float* __restrict__ b_loc,
    float* __restrict__ cst)
{
  __shared__ float qv[DD], kqv[DD], tv[DD], uv[DD];
  const int tid = threadIdx.x, wave = tid >> 6, lane = tid & 63;

  if (wave == 0) {              // q = seed @ Wq
    float a = 0.f;
#pragma unroll
    for (int e = 0; e < DD; ++e) a += seed[e] * Wq[e * DD + lane];
    qv[lane] = a;
  } else {                      // t = Wo @ wl2
    float a = 0.f;
#pragma unroll
    for (int j = 0; j < DD; ++j) a += Wo[lane * DD + j] * w_loc[4 + j];
    tv[lane] = a;
  }
  __syncthreads();
  if (wave == 0) {              // kq = Wk @ q
    float a = 0.f;
#pragma unroll
    for (int d = 0; d < DD; ++d) a += Wk[lane * DD + d] * qv[d];
    kqv[lane] = a;
  } else {                      // u = Wv @ t
    float a = 0.f;
#pragma unroll
    for (int j = 0; j < DD; ++j) a += Wv[lane * DD + j] * tv[j];
    uv[lane] = a;
  }
  __syncthreads();
  if (tid < 4) {                // c4
    float a = 0.f;
#pragma unroll
    for (int e = 0; e < DD; ++e) a += W_in[tid * DD + e] * kqv[e];
    cst[tid] = a;
  } else if (tid == 4) {        // c0
    float a = 0.f;
#pragma unroll
    for (int e = 0; e < DD; ++e) a += b_in[e] * kqv[e];
    cst[4] = a;
  } else if (tid >= 5 && tid < 9) {  // d4
    float a = 0.f;
#pragma unroll
    for (int e = 0; e < DD; ++e) a += W_in[(tid - 5) * DD + e] * uv[e];
    cst[tid] = a;
  } else if (tid == 9) {        // d0
    float a = 0.f;
#pragma unroll
    for (int e = 0; e < DD; ++e) a += b_in[e] * uv[e] + b_o[e] * w_loc[4 + e];
    cst[9] = a + b_loc[0];
  }
}

// ---------------------------------------------------------------------------
// Kernel 2: one WAVE per batch. 16 rows/lane, zero __syncthreads, zero LDS.
// All reductions are 64-lane shuffle trees; lane 0 solves the 4x4 in double.
// ---------------------------------------------------------------------------
__global__ __launch_bounds__(256) void wls_wave(
    const float* __restrict__ x,       // B*M*4
    const int*   __restrict__ pad,     // B*M
    const float* __restrict__ w_loc,   // 68
    const float* __restrict__ prelu_a, // 1
    const float* __restrict__ cst,     // 10 (in d_ws)
    float* __restrict__ out)           // B*4
{
  const int lane = threadIdx.x & 63;
  const int wv   = threadIdx.x >> 6;
  const int b    = (blockIdx.x << 2) | wv;

  // uniform constants (latency-critical: issue first)
  const float c40 = cst[0], c41 = cst[1], c42 = cst[2], c43 = cst[3], c0 = cst[4];
  const float d40 = cst[5], d41 = cst[6], d42 = cst[7], d43 = cst[8], d0 = cst[9];
  const float wl0 = w_loc[0], wl1 = w_loc[1], wl2 = w_loc[2], wl3 = w_loc[3];
  const float aP  = prelu_a[0];

  // this wave's batch: 1024 rows, lane handles rows lane, lane+64, ... (coalesced)
  const float4* x4 = (const float4*)(x + (size_t)b * (MM * 4));
  const int*    pd = pad + (size_t)b * MM;

  float4 xr[16];
  int    mk[16];
#pragma unroll
  for (int r = 0; r < 16; ++r) xr[r] = x4[lane + (r << 6)];
#pragma unroll
  for (int r = 0; r < 16; ++r) mk[r] = pd[lane + (r << 6)];

  // ---- scores + wave max (butterfly: all lanes get it) ----
  float sc[16];
  float pmax = -INFINITY;
#pragma unroll
  for (int r = 0; r < 16; ++r) {
    float s = (xr[r].x * c40 + xr[r].y * c41 + xr[r].z * c42 + xr[r].w * c43 + c0) * 0.125f;
    s = mk[r] ? NEG_INF_F : s;
    sc[r] = s;
    pmax = fmaxf(pmax, s);
  }
#pragma unroll
  for (int o = 32; o > 0; o >>= 1) pmax = fmaxf(pmax, __shfl_xor(pmax, o));

  // ---- softmax partials Z, sum(e*x) (butterfly: all lanes need them) ----
  float se = 0.f, sx0 = 0.f, sx1 = 0.f, sx2 = 0.f, sx3 = 0.f;
#pragma unroll
  for (int r = 0; r < 16; ++r) {
    const float e = __expf(sc[r] - pmax);  // masked rows -> 0 (all-masked -> uniform)
    se += e;
    sx0 += e * xr[r].x; sx1 += e * xr[r].y; sx2 += e * xr[r].z; sx3 += e * xr[r].w;
  }
#pragma unroll
  for (int o = 32; o > 0; o >>= 1) {
    se  += __shfl_xor(se, o);
    sx0 += __shfl_xor(sx0, o); sx1 += __shfl_xor(sx1, o);
    sx2 += __shfl_xor(sx2, o); sx3 += __shfl_xor(sx3, o);
  }
  const float invZ = 1.f / se;
  const float sB = (sx0 * d40 + sx1 * d41 + sx2 * d42 + sx3 * d43) * invZ + d0;

  // ---- WLS accumulation: G = sum w^2 a a^T (10) + rhs (4), a=(-x1,-x2,-x3,1), r=x0
  float g0 = 0.f, g1 = 0.f, g2 = 0.f, g3 = 0.f, g4 = 0.f, g5 = 0.f, g6 = 0.f,
        g7 = 0.f, g8 = 0.f, g9 = 0.f, r0 = 0.f, r1 = 0.f, r2 = 0.f, r3 = 0.f;
#pragma unroll
  for (int r = 0; r < 16; ++r) {
    const float x0 = xr[r].x, x1 = xr[r].y, x2 = xr[r].z, x3 = xr[r].w;
    float z = x0 * wl0 + x1 * wl1 + x2 * wl2 + x3 * wl3 + sB;
    float w = (z >= 0.f) ? z : aP * z;
    w = mk[r] ? 0.f : w;
    const float w2 = w * w;
    g0 += w2 * x1 * x1; g1 += w2 * x1 * x2; g2 += w2 * x1 * x3; g3 -= w2 * x1;
    g4 += w2 * x2 * x2; g5 += w2 * x2 * x3; g6 -= w2 * x2;
    g7 += w2 * x3 * x3; g8 -= w2 * x3;
    g9 += w2;
    r0 -= w2 * x1 * x0; r1 -= w2 * x2 * x0; r2 -= w2 * x3 * x0; r3 += w2 * x0;
  }
  float vals[14] = {g0, g1, g2, g3, g4, g5, g6, g7, g8, g9, r0, r1, r2, r3};
#pragma unroll
  for (int j = 0; j < 14; ++j) {
#pragma unroll
    for (int o = 32; o > 0; o >>= 1) vals[j] += __shfl_down(vals[j], o);
  }

  // ---- lane 0: 4x4 normal-equations solve (double GE, partial pivoting) ----
  if (lane == 0) {
    double G[4][5];
    G[0][0] = vals[0]; G[0][1] = vals[1]; G[0][2] = vals[2]; G[0][3] = vals[3]; G[0][4] = vals[10];
    G[1][0] = vals[1]; G[1][1] = vals[4]; G[1][2] = vals[5]; G[1][3] = vals[6]; G[1][4] = vals[11];
    G[2][0] = vals[2]; G[2][1] = vals[5]; G[2][2] = vals[7]; G[2][3] = vals[8]; G[2][4] = vals[12];
    G[3][0] = vals[3]; G[3][1] = vals[6]; G[3][2] = vals[8]; G[3][3] = vals[9]; G[3][4] = vals[13];

    for (int c = 0; c < 4; ++c) {
      int p = c; double mv = fabs(G[c][c]);
      for (int rr = c + 1; rr < 4; ++rr)
        if (fabs(G[rr][c]) > mv) { mv = fabs(G[rr][c]); p = rr; }
      if (p != c)
        for (int j = c; j < 5; ++j) { double t = G[c][j]; G[c][j] = G[p][j]; G[p][j] = t; }
      const double inv = 1.0 / G[c][c];
      for (int rr = c + 1; rr < 4; ++rr) {
        const double f = G[rr][c] * inv;
        for (int j = c; j < 5; ++j) G[rr][j] -= f * G[c][j];
      }
    }
    double y[4];
    for (int c = 3; c >= 0; --c) {
      double acc = G[c][4];
      for (int j = c + 1; j < 4; ++j) acc -= G[c][j] * y[j];
      y[c] = acc / G[c][c];
    }
    float4 o4;
    o4.x = (float)y[0]; o4.y = (float)y[1]; o4.z = (float)y[2]; o4.w = (float)y[3];
    *(float4*)(out + (size_t)b * 4) = o4;
  }
}

extern "C" void kernel_launch(void* const* d_in, const int* in_sizes, int n_in,
                              void* d_out, int out_size, void* d_ws, size_t ws_size,
                              hipStream_t stream) {
  const float* x       = (const float*)d_in[0];
  const int*   pad     = (const int*)d_in[1];
  const float* W_in    = (const float*)d_in[2];
  const float* b_in    = (const float*)d_in[3];
  const float* seed    = (const float*)d_in[4];
  const float* Wq      = (const float*)d_in[5];
  const float* Wk      = (const float*)d_in[6];
  const float* Wv      = (const float*)d_in[7];
  const float* Wo      = (const float*)d_in[8];
  const float* b_o     = (const float*)d_in[9];
  const float* w_loc   = (const float*)d_in[10];
  const float* b_loc   = (const float*)d_in[11];
  const float* prelu_a = (const float*)d_in[12];
  float* out = (float*)d_out;
  float* cst = (float*)d_ws;   // 10 floats

  consts_kernel<<<dim3(1), dim3(128), 0, stream>>>(
      W_in, b_in, seed, Wq, Wk, Wv, Wo, b_o, w_loc, b_loc, cst);
  wls_wave<<<dim3(BB / 4), dim3(256), 0, stream>>>(
      x, pad, w_loc, prelu_a, cst, out);
}

// Round 9
// 111.515 us; speedup vs baseline: 1.1866x; 1.0539x over previous
//
#include <hip/hip_runtime.h>
#include <math.h>

#define BB 2048
#define MM 1024
#define DD 64
#define NEG_INF_F (-1e30f)

// ---------------------------------------------------------------------------
// Kernel 1: one block computes the 10 batch-independent constants into d_ws.
//   c4 = W_in @ (Wk @ (seed @ Wq)),  c0 = b_in . (Wk @ q)     [score collapse]
//   d4 = W_in @ (Wv @ (Wo @ wl2)),   d0 = b_in.u + b_o.wl2 + b_loc  [sB collapse]
// ---------------------------------------------------------------------------
__global__ __launch_bounds__(128) void consts_kernel(
    const float* __restrict__ W_in, const float* __restrict__ b_in,
    const float* __restrict__ seed, const float* __restrict__ Wq,
    const float* __restrict__ Wk,   const float* __restrict__ Wv,
    const float* __restrict__ Wo,   const float* __restrict__ b_o,
    const float* __restrict__ w_loc, const float* __restrict__ b_loc,
    float* __restrict__ cst)
{
  __shared__ float qv[DD], kqv[DD], tv[DD], uv[DD];
  const int tid = threadIdx.x, wave = tid >> 6, lane = tid & 63;

  if (wave == 0) {              // q = seed @ Wq
    float a = 0.f;
#pragma unroll
    for (int e = 0; e < DD; ++e) a += seed[e] * Wq[e * DD + lane];
    qv[lane] = a;
  } else {                      // t = Wo @ wl2
    float a = 0.f;
#pragma unroll
    for (int j = 0; j < DD; ++j) a += Wo[lane * DD + j] * w_loc[4 + j];
    tv[lane] = a;
  }
  __syncthreads();
  if (wave == 0) {              // kq = Wk @ q
    float a = 0.f;
#pragma unroll
    for (int d = 0; d < DD; ++d) a += Wk[lane * DD + d] * qv[d];
    kqv[lane] = a;
  } else {                      // u = Wv @ t
    float a = 0.f;
#pragma unroll
    for (int j = 0; j < DD; ++j) a += Wv[lane * DD + j] * tv[j];
    uv[lane] = a;
  }
  __syncthreads();
  if (tid < 4) {                // c4
    float a = 0.f;
#pragma unroll
    for (int e = 0; e < DD; ++e) a += W_in[tid * DD + e] * kqv[e];
    cst[tid] = a;
  } else if (tid == 4) {        // c0
    float a = 0.f;
#pragma unroll
    for (int e = 0; e < DD; ++e) a += b_in[e] * kqv[e];
    cst[4] = a;
  } else if (tid >= 5 && tid < 9) {  // d4
    float a = 0.f;
#pragma unroll
    for (int e = 0; e < DD; ++e) a += W_in[(tid - 5) * DD + e] * uv[e];
    cst[tid] = a;
  } else if (tid == 9) {        // d0
    float a = 0.f;
#pragma unroll
    for (int e = 0; e < DD; ++e) a += b_in[e] * uv[e] + b_o[e] * w_loc[4 + e];
    cst[9] = a + b_loc[0];
  }
}

// ---------------------------------------------------------------------------
// Kernel 2: one WAVE per batch, zero barriers/LDS; shuffle-tree reductions.
// Final 4x4 SPD solve: fully-unrolled fp64 CHOLESKY with named scalars only
// (no arrays -> no scratch; the round-6/8 pivoted-GE used runtime-indexed
//  double G[4][5] which lived in scratch and serialized ~30us per wave).
// ---------------------------------------------------------------------------
__global__ __launch_bounds__(256) void wls_wave(
    const float* __restrict__ x,       // B*M*4
    const int*   __restrict__ pad,     // B*M
    const float* __restrict__ w_loc,   // 68
    const float* __restrict__ prelu_a, // 1
    const float* __restrict__ cst,     // 10 (in d_ws)
    float* __restrict__ out)           // B*4
{
  const int lane = threadIdx.x & 63;
  const int wv   = threadIdx.x >> 6;
  const int b    = (blockIdx.x << 2) | wv;

  const float c40 = cst[0], c41 = cst[1], c42 = cst[2], c43 = cst[3], c0 = cst[4];
  const float d40 = cst[5], d41 = cst[6], d42 = cst[7], d43 = cst[8], d0 = cst[9];
  const float wl0 = w_loc[0], wl1 = w_loc[1], wl2 = w_loc[2], wl3 = w_loc[3];
  const float aP  = prelu_a[0];

  const float4* x4 = (const float4*)(x + (size_t)b * (MM * 4));
  const int*    pd = pad + (size_t)b * MM;

  float4 xr[16];
  int    mk[16];
#pragma unroll
  for (int r = 0; r < 16; ++r) xr[r] = x4[lane + (r << 6)];
#pragma unroll
  for (int r = 0; r < 16; ++r) mk[r] = pd[lane + (r << 6)];

  // ---- scores + wave max ----
  float sc[16];
  float pmax = -INFINITY;
#pragma unroll
  for (int r = 0; r < 16; ++r) {
    float s = (xr[r].x * c40 + xr[r].y * c41 + xr[r].z * c42 + xr[r].w * c43 + c0) * 0.125f;
    s = mk[r] ? NEG_INF_F : s;
    sc[r] = s;
    pmax = fmaxf(pmax, s);
  }
#pragma unroll
  for (int o = 32; o > 0; o >>= 1) pmax = fmaxf(pmax, __shfl_xor(pmax, o));

  // ---- softmax partials Z, sum(e*x) ----
  float se = 0.f, sx0 = 0.f, sx1 = 0.f, sx2 = 0.f, sx3 = 0.f;
#pragma unroll
  for (int r = 0; r < 16; ++r) {
    const float e = __expf(sc[r] - pmax);  // masked rows -> 0
    se += e;
    sx0 += e * xr[r].x; sx1 += e * xr[r].y; sx2 += e * xr[r].z; sx3 += e * xr[r].w;
  }
#pragma unroll
  for (int o = 32; o > 0; o >>= 1) {
    se  += __shfl_xor(se, o);
    sx0 += __shfl_xor(sx0, o); sx1 += __shfl_xor(sx1, o);
    sx2 += __shfl_xor(sx2, o); sx3 += __shfl_xor(sx3, o);
  }
  const float invZ = 1.f / se;
  const float sB = (sx0 * d40 + sx1 * d41 + sx2 * d42 + sx3 * d43) * invZ + d0;

  // ---- WLS partials: G = sum w^2 a a^T (10) + rhs (4); a=(-x1,-x2,-x3,1), r=x0
  float g0 = 0.f, g1 = 0.f, g2 = 0.f, g3 = 0.f, g4 = 0.f, g5 = 0.f, g6 = 0.f,
        g7 = 0.f, g8 = 0.f, g9 = 0.f, r0 = 0.f, r1 = 0.f, r2 = 0.f, r3 = 0.f;
#pragma unroll
  for (int r = 0; r < 16; ++r) {
    const float x0 = xr[r].x, x1 = xr[r].y, x2 = xr[r].z, x3 = xr[r].w;
    float z = x0 * wl0 + x1 * wl1 + x2 * wl2 + x3 * wl3 + sB;
    float w = (z >= 0.f) ? z : aP * z;
    w = mk[r] ? 0.f : w;
    const float w2 = w * w;
    g0 += w2 * x1 * x1; g1 += w2 * x1 * x2; g2 += w2 * x1 * x3; g3 -= w2 * x1;
    g4 += w2 * x2 * x2; g5 += w2 * x2 * x3; g6 -= w2 * x2;
    g7 += w2 * x3 * x3; g8 -= w2 * x3;
    g9 += w2;
    r0 -= w2 * x1 * x0; r1 -= w2 * x2 * x0; r2 -= w2 * x3 * x0; r3 += w2 * x0;
  }
  float vals[14] = {g0, g1, g2, g3, g4, g5, g6, g7, g8, g9, r0, r1, r2, r3};
#pragma unroll
  for (int j = 0; j < 14; ++j) {
#pragma unroll
    for (int o = 32; o > 0; o >>= 1) vals[j] += __shfl_down(vals[j], o);
  }

  // ---- lane 0: unpivoted fp64 Cholesky, fully static (registers only) ----
  if (lane == 0) {
    const double G00 = vals[0], G01 = vals[1], G02 = vals[2], G03 = vals[3];
    const double G11 = vals[4], G12 = vals[5], G13 = vals[6];
    const double G22 = vals[7], G23 = vals[8];
    const double G33 = vals[9];
    const double b0 = vals[10], b1 = vals[11], b2 = vals[12], b3 = vals[13];

    // L (lower) such that G = L L^T
    const double L00 = sqrt(G00);
    const double iL00 = 1.0 / L00;
    const double L10 = G01 * iL00;
    const double L20 = G02 * iL00;
    const double L30 = G03 * iL00;
    const double L11 = sqrt(G11 - L10 * L10);
    const double iL11 = 1.0 / L11;
    const double L21 = (G12 - L20 * L10) * iL11;
    const double L31 = (G13 - L30 * L10) * iL11;
    const double L22 = sqrt(G22 - L20 * L20 - L21 * L21);
    const double iL22 = 1.0 / L22;
    const double L32 = (G23 - L30 * L20 - L31 * L21) * iL22;
    const double L33 = sqrt(G33 - L30 * L30 - L31 * L31 - L32 * L32);
    const double iL33 = 1.0 / L33;

    // forward: L y = b
    const double y0 = b0 * iL00;
    const double y1 = (b1 - L10 * y0) * iL11;
    const double y2 = (b2 - L20 * y0 - L21 * y1) * iL22;
    const double y3 = (b3 - L30 * y0 - L31 * y1 - L32 * y2) * iL33;

    // backward: L^T s = y
    const double s3 = y3 * iL33;
    const double s2 = (y2 - L32 * s3) * iL22;
    const double s1 = (y1 - L21 * s2 - L31 * s3) * iL11;
    const double s0 = (y0 - L10 * s1 - L20 * s2 - L30 * s3) * iL00;

    float4 o4;
    o4.x = (float)s0; o4.y = (float)s1; o4.z = (float)s2; o4.w = (float)s3;
    *(float4*)(out + (size_t)b * 4) = o4;
  }
}

extern "C" void kernel_launch(void* const* d_in, const int* in_sizes, int n_in,
                              void* d_out, int out_size, void* d_ws, size_t ws_size,
                              hipStream_t stream) {
  const float* x       = (const float*)d_in[0];
  const int*   pad     = (const int*)d_in[1];
  const float* W_in    = (const float*)d_in[2];
  const float* b_in    = (const float*)d_in[3];
  const float* seed    = (const float*)d_in[4];
  const float* Wq      = (const float*)d_in[5];
  const float* Wk      = (const float*)d_in[6];
  const float* Wv      = (const float*)d_in[7];
  const float* Wo      = (const float*)d_in[8];
  const float* b_o     = (const float*)d_in[9];
  const float* w_loc   = (const float*)d_in[10];
  const float* b_loc   = (const float*)d_in[11];
  const float* prelu_a = (const float*)d_in[12];
  float* out = (float*)d_out;
  float* cst = (float*)d_ws;   // 10 floats

  consts_kernel<<<dim3(1), dim3(128), 0, stream>>>(
      W_in, b_in, seed, Wq, Wk, Wv, Wo, b_o, w_loc, b_loc, cst);
  wls_wave<<<dim3(BB / 4), dim3(256), 0, stream>>>(
      x, pad, w_loc, prelu_a, cst, out);
}